// Round 8
// baseline (305.855 us; speedup 1.0000x reference)
//
#include <hip/hip_runtime.h>
#include <math.h>

#define B_ 64
#define T_ 577
#define E_ 768
#define H_ 64
#define N_ 576
#define GW_ 24

typedef float f32x4 __attribute__((ext_vector_type(4)));
typedef __bf16 bf16x8 __attribute__((ext_vector_type(8)));
typedef __bf16 bf16x4 __attribute__((ext_vector_type(4)));

__device__ inline void split_bf16(float f, __bf16& h, __bf16& l) {
  h = (__bf16)f;
  l = (__bf16)(f - (float)h);
}

__device__ inline float bperm_f(int byte_addr, float x) {
  return __int_as_float(__builtin_amdgcn_ds_bpermute(byte_addr, __float_as_int(x)));
}

// Direct global->LDS DMA, 16 B per lane. LDS dest = wave-uniform base + lane*16.
#define GLOAD_LDS16(G, L)                                                     \
  __builtin_amdgcn_global_load_lds(                                           \
      (const __attribute__((address_space(1))) void*)(G),                     \
      (__attribute__((address_space(3))) void*)(L), 16, 0, 0)

// -------------------- Kernel 0: W -> split-bf16, slot-permuted chunk layout --------------------
// Chunk kc = 12288 bf16: hi[6144] then lo[6144]. Value W[kc*32+g*8+j][n] lives at
// slot(n,g)*8 + j with slot = n*4 + (g ^ (n&3) ^ ((n>>2)&3)).
// The XOR makes the *linear* LDS copy (global_load_lds) conflict-free on the b128 frag reads
// (64 lanes spread exactly 8 per bank-group — same spread the old pad-40 layout achieved).
__global__ __launch_bounds__(256) void prep_w_kernel(
    const float* __restrict__ wq, const float* __restrict__ wk, const float* __restrict__ wv,
    __bf16* __restrict__ wsw2)
{
  int t = blockIdx.x * 256 + threadIdx.x;
  if (t >= 24*192) return;
  int kc = t / 192, n = t - kc*192;
  const float* src = (n < 64) ? wq : ((n < 128) ? wk : wv);
  int nn = n & 63;
  int xb = (n & 3) ^ ((n >> 2) & 3);
  size_t cbase = (size_t)kc * 12288;
  #pragma unroll
  for (int g = 0; g < 4; ++g) {
    __bf16 hb[8], lb[8];
    #pragma unroll
    for (int j = 0; j < 8; ++j) {
      float f = src[(size_t)(kc*32 + g*8 + j)*64 + nn];
      split_bf16(f, hb[j], lb[j]);
    }
    int slot = n*4 + (g ^ xb);
    *(bf16x8*)(wsw2 + cbase + slot*8)        = *(bf16x8*)hb;
    *(bf16x8*)(wsw2 + cbase + 6144 + slot*8) = *(bf16x8*)lb;
  }
}

// -------------------- Kernel 1: MFMA qkv + LN + heads (R1 structure + gload_lds B) ----------
// 577 blocks x 64 rows, 4 waves. A: reg-prefetch + pad-40 LDS (unchanged).
// B: global_load_lds width-16 into a DOUBLE-BUFFERED dense region, issued after the 2nd
// barrier so the DMA flies across the MFMA phase and is drained by the next __syncthreads.
__global__ __launch_bounds__(256) void qkv_ln_kernel(
    const float* __restrict__ x, const __bf16* __restrict__ wsw2,
    const float* __restrict__ qg, const float* __restrict__ qb,
    const float* __restrict__ kg, const float* __restrict__ kb,
    const float* __restrict__ wsig, const float* __restrict__ bsig,
    const float* __restrict__ walp, const float* __restrict__ balp,
    float* __restrict__ qo, float* __restrict__ ko, float* __restrict__ vo,
    float* __restrict__ alo, float* __restrict__ sxo, float* __restrict__ syo)
{
  // stage: A 64x40 hi/lo (5120 el) + B dbuf 2x12288 el = 29696 bf16 = 59392 B.
  // epilogue aliases as C tile 64x193 f32 + stats (12608 floats < 14848).
  __shared__ __align__(16) float smem[14848];
  __bf16* A_hi = (__bf16*)smem;            // 64 x 40
  __bf16* A_lo = A_hi + 2560;
  __bf16* B0   = A_lo + 2560;              // 12288 el each
  __bf16* B1   = B0 + 12288;
  float (*Cs)[193] = (float (*)[193])smem;
  float* mu_q = smem + 64*193;
  float* rs_q = mu_q + 64;
  float* mu_k = rs_q + 64;
  float* rs_k = mu_k + 64;

  const int tid  = threadIdx.x;
  const int lane = tid & 63;
  const int w    = tid >> 6;
  const int quad = lane >> 4;
  const int m    = lane & 15;
  const int rowbase = blockIdx.x << 6;

  f32x4 acc[4][3];
  #pragma unroll
  for (int mt = 0; mt < 4; ++mt)
    #pragma unroll
    for (int nt = 0; nt < 3; ++nt)
      acc[mt][nt] = (f32x4){0.f, 0.f, 0.f, 0.f};

  const int kfrag = quad * 8;
  const int xl    = quad ^ (m & 3) ^ (m >> 2);   // per-lane B slot xor

  // A prefetch registers (depth 1, as R1)
  float4 xr0, xr1;
  const int arow0 = tid >> 3,        ak0 = (tid & 7) * 4;
  const int arow1 = (tid + 256) >> 3, ak1 = (tid & 7) * 4;

  auto load_A = [&](int kc) {
    xr0 = *(const float4*)(x + (size_t)(rowbase + arow0)*E_ + kc*32 + ak0);
    xr1 = *(const float4*)(x + (size_t)(rowbase + arow1)*E_ + kc*32 + ak1);
  };
  auto store_A = [&]() {
    __bf16 h0,l0,h1,l1,h2,l2,h3,l3;
    split_bf16(xr0.x,h0,l0); split_bf16(xr0.y,h1,l1);
    split_bf16(xr0.z,h2,l2); split_bf16(xr0.w,h3,l3);
    *(bf16x4*)&A_hi[arow0*40 + ak0] = (bf16x4){h0,h1,h2,h3};
    *(bf16x4*)&A_lo[arow0*40 + ak0] = (bf16x4){l0,l1,l2,l3};
    split_bf16(xr1.x,h0,l0); split_bf16(xr1.y,h1,l1);
    split_bf16(xr1.z,h2,l2); split_bf16(xr1.w,h3,l3);
    *(bf16x4*)&A_hi[arow1*40 + ak1] = (bf16x4){h0,h1,h2,h3};
    *(bf16x4*)&A_lo[arow1*40 + ak1] = (bf16x4){l0,l1,l2,l3};
  };
  // per wave: 6 calls x 1024 B = 1/4 of the 24576-B chunk
  auto issue_B = [&](int kc, __bf16* Bbuf) {
    const __bf16* sbase = wsw2 + (size_t)kc*12288 + (size_t)(w*6)*512 + lane*8;
    __bf16* dbase = Bbuf + (w*6)*512;
    #pragma unroll
    for (int j = 0; j < 6; ++j)
      GLOAD_LDS16(sbase + j*512, dbase + j*512);
  };

  issue_B(0, B0);
  load_A(0);
  #pragma unroll 1
  for (int kc = 0; kc < 24; ++kc) {
    __bf16* Bcur = (kc & 1) ? B1 : B0;
    __bf16* Bnxt = (kc & 1) ? B0 : B1;
    __syncthreads();          // drains vmcnt: B(kc) DMA done, A(kc) regs ready; prev readers done
    store_A();
    __syncthreads();          // A visible (nothing in VMEM flight here -> cheap drain)
    if (kc < 23) {            // B(kc+1) DMA + A(kc+1) loads fly across the MFMA phase
      issue_B(kc + 1, Bnxt);
      load_A(kc + 1);
    }

    bf16x8 bh[3], bl[3];
    #pragma unroll
    for (int nt = 0; nt < 3; ++nt) {
      int slotb = (w*48 + nt*16 + m)*4 + xl;
      bh[nt] = *(const bf16x8*)&Bcur[slotb*8];
      bl[nt] = *(const bf16x8*)&Bcur[6144 + slotb*8];
    }
    #pragma unroll
    for (int mt = 0; mt < 4; ++mt) {
      bf16x8 ah = *(const bf16x8*)&A_hi[(mt*16 + m)*40 + kfrag];
      bf16x8 al = *(const bf16x8*)&A_lo[(mt*16 + m)*40 + kfrag];
      #pragma unroll
      for (int nt = 0; nt < 3; ++nt) {
        acc[mt][nt] = __builtin_amdgcn_mfma_f32_16x16x32_bf16(ah, bh[nt], acc[mt][nt], 0, 0, 0);
        acc[mt][nt] = __builtin_amdgcn_mfma_f32_16x16x32_bf16(al, bh[nt], acc[mt][nt], 0, 0, 0);
        acc[mt][nt] = __builtin_amdgcn_mfma_f32_16x16x32_bf16(ah, bl[nt], acc[mt][nt], 0, 0, 0);
      }
    }
  }
  __syncthreads();   // all LDS frag reads done before aliasing as C tile

  #pragma unroll
  for (int mt = 0; mt < 4; ++mt)
    #pragma unroll
    for (int nt = 0; nt < 3; ++nt) {
      int row = mt*16 + quad*4;
      int col = w*48 + nt*16 + m;
      Cs[row + 0][col] = acc[mt][nt].x;
      Cs[row + 1][col] = acc[mt][nt].y;
      Cs[row + 2][col] = acc[mt][nt].z;
      Cs[row + 3][col] = acc[mt][nt].w;
    }
  __syncthreads();

  // stats: wave0 -> q rows, wave1 -> k rows (parallel)
  if (tid < 64) {
    float s = 0.f;
    for (int h = 0; h < 64; ++h) s += Cs[tid][h];
    float mu = s * (1.f/64.f);
    float vs = 0.f;
    for (int h = 0; h < 64; ++h) { float d = Cs[tid][h] - mu; vs += d*d; }
    mu_q[tid] = mu;
    rs_q[tid] = rsqrtf(vs*(1.f/64.f) + 1e-5f);
  } else if (tid < 128) {
    int r = tid - 64;
    float s = 0.f;
    for (int h = 0; h < 64; ++h) s += Cs[r][64+h];
    float mu = s * (1.f/64.f);
    float vs = 0.f;
    for (int h = 0; h < 64; ++h) { float d = Cs[r][64+h] - mu; vs += d*d; }
    mu_k[r] = mu;
    rs_k[r] = rsqrtf(vs*(1.f/64.f) + 1e-5f);
  }
  __syncthreads();

  // heads on wave 3 (rows = tid-192), LN-apply on everyone
  if (tid >= 192) {
    int r = tid - 192;
    int mrow = rowbase + r;
    int tindex = mrow % T_;
    if (tindex >= 1) {
      int bb = mrow / T_;
      int g = tindex - 1;
      float mu = mu_q[r], rs = rs_q[r];
      float za = 0.f, z0 = 0.f, z1 = 0.f;
      for (int h = 0; h < 64; ++h) {
        float qv = (Cs[r][h] - mu) * rs * qg[h] + qb[h];
        za += qv * walp[h];
        z0 += qv * wsig[2*h];
        z1 += qv * wsig[2*h+1];
      }
      za += balp[0]; z0 += bsig[0]; z1 += bsig[1];
      float al = fmaxf(za, 0.f) + log1pf(__expf(-fabsf(za)));
      float sx = 1.f/(1.f + __expf(-z0));
      float sy = 1.f/(1.f + __expf(-z1));
      alo[bb*N_ + g] = al;
      sxo[bb*N_ + g] = 0.5f/(sx*sx);
      syo[bb*N_ + g] = 0.5f/(sy*sy);
    }
  }
  // LN-apply + store q,k,v (float4 per thread-iteration)
  for (int idx = tid; idx < 64*48; idx += 256) {
    int r = idx / 48, c4 = (idx - (idx/48)*48) * 4;
    size_t row = (size_t)rowbase + r;
    float4 val = make_float4(Cs[r][c4], Cs[r][c4+1], Cs[r][c4+2], Cs[r][c4+3]);
    if (c4 < 64) {
      float mu = mu_q[r], rs = rs_q[r];
      float4 o;
      o.x = (val.x - mu)*rs*qg[c4+0] + qb[c4+0];
      o.y = (val.y - mu)*rs*qg[c4+1] + qb[c4+1];
      o.z = (val.z - mu)*rs*qg[c4+2] + qb[c4+2];
      o.w = (val.w - mu)*rs*qg[c4+3] + qb[c4+3];
      *(float4*)(qo + row*64 + c4) = o;
    } else if (c4 < 128) {
      int h = c4 - 64;
      float mu = mu_k[r], rs = rs_k[r];
      float4 o;
      o.x = (val.x - mu)*rs*kg[h+0] + kb[h+0];
      o.y = (val.y - mu)*rs*kg[h+1] + kb[h+1];
      o.z = (val.z - mu)*rs*kg[h+2] + kb[h+2];
      o.w = (val.w - mu)*rs*kg[h+3] + kb[h+3];
      *(float4*)(ko + row*64 + h) = o;
    } else {
      *(float4*)(vo + row*64 + (c4-128)) = val;
    }
  }
}

// -------------------- Kernel 2: swapped-operand MFMA flash attention (unchanged) ----------
__global__ __launch_bounds__(256, 4) void attn_kernel(
    const float* __restrict__ q, const float* __restrict__ k, const float* __restrict__ v,
    const float* __restrict__ ala, const float* __restrict__ sxa, const float* __restrict__ sya,
    float* __restrict__ out)
{
  __shared__ __align__(16) __bf16 sm[4*4608];   // 4 regions of 64x72
  __bf16* KH = sm;            __bf16* KL = sm + 4608;
  __bf16* VH = sm + 2*4608;   __bf16* VL = sm + 3*4608;   // V^T: [dim][key]

  const int tid  = threadIdx.x;
  const int lane = tid & 63;
  const int w    = tid >> 6;
  const int quad = lane >> 4;
  const int m    = lane & 15;

  // XCD-aware bijective remap of 640 blocks (8 XCDs x 80)
  const int f       = blockIdx.y * 10 + blockIdx.x;
  const int logical = (f & 7) * 80 + (f >> 3);
  const int b       = logical / 10;
  const int qt      = logical - b * 10;

  const float* qbase = q + (size_t)b * T_ * H_;
  const float* kbase = k + (size_t)b * T_ * H_;
  const float* vbase = v + (size_t)b * T_ * H_;

  // ---- per-lane q-row parameters ----
  const int  row    = qt*64 + w*16 + m;
  const int  rowc   = row < T_ ? row : T_ - 1;
  const bool qvalid = row < T_;
  const bool qhas   = (row >= 1) && qvalid;
  float al = 0.f, isx = 0.f, isy = 0.f, qr = 0.f, qc = 0.f;
  {
    int g = qhas ? row - 1 : 0;
    if (qhas) {
      al  = ala[b*N_ + g] * 0.125f;
      isx = sxa[b*N_ + g];
      isy = sya[b*N_ + g];
      int gr = g / GW_;
      qr = (float)gr;
      qc = (float)(g - gr*GW_);
    }
  }

  // ---- Q into registers, pre-scaled by 1/8, hi/lo split ----
  bf16x8 qh[2], ql[2];
  #pragma unroll
  for (int ks = 0; ks < 2; ++ks) {
    float4 f0 = *(const float4*)(qbase + (size_t)rowc*H_ + ks*32 + quad*8);
    float4 f1 = *(const float4*)(qbase + (size_t)rowc*H_ + ks*32 + quad*8 + 4);
    float fv[8] = {f0.x, f0.y, f0.z, f0.w, f1.x, f1.y, f1.z, f1.w};
    #pragma unroll
    for (int j = 0; j < 8; ++j) {
      float s = fv[j] * 0.125f;
      __bf16 h, l;
      split_bf16(s, h, l);
      qh[ks][j] = h;
      ql[ks][j] = l;
    }
  }

  float mo = -INFINITY, lsum = 0.f;
  f32x4 acc[4];   // O^T: acc[nt].reg = O[d = nt*16+quad*4+reg][q = w*16+m]
  #pragma unroll
  for (int nt = 0; nt < 4; ++nt) acc[nt] = (f32x4){0.f, 0.f, 0.f, 0.f};

  const int  addrA = ((2*(quad & 1))*16 + m) * 4;
  const int  addrB = addrA + 64;
  const bool hiNT  = quad >= 2;

  float4 kreg[4];
  float  vreg[16];
  const int d0 = tid & 15, k0 = (tid >> 4) * 4;

  auto load_kv = [&](int kt) {
    #pragma unroll
    for (int i = 0; i < 4; ++i) {
      int s = tid + 256*i;
      int key = s >> 4, c4 = (s & 15)*4;
      int kgl = kt*64 + key;
      int kcl = kgl < T_ ? kgl : T_ - 1;
      kreg[i] = *(const float4*)(kbase + (size_t)kcl*H_ + c4);
    }
    #pragma unroll
    for (int di = 0; di < 4; ++di)
      #pragma unroll
      for (int ki = 0; ki < 4; ++ki) {
        int kgl = kt*64 + k0 + ki;
        int kcl = kgl < T_ ? kgl : T_ - 1;
        vreg[di*4+ki] = vbase[(size_t)kcl*H_ + d0 + 16*di];
      }
  };
  auto store_kv = [&]() {
    #pragma unroll
    for (int i = 0; i < 4; ++i) {
      int s = tid + 256*i;
      int key = s >> 4, c4 = (s & 15)*4;
      __bf16 h0,l0,h1,l1,h2,l2,h3,l3;
      split_bf16(kreg[i].x,h0,l0); split_bf16(kreg[i].y,h1,l1);
      split_bf16(kreg[i].z,h2,l2); split_bf16(kreg[i].w,h3,l3);
      *(bf16x4*)&KH[key*72 + c4] = (bf16x4){h0,h1,h2,h3};
      *(bf16x4*)&KL[key*72 + c4] = (bf16x4){l0,l1,l2,l3};
    }
    #pragma unroll
    for (int di = 0; di < 4; ++di) {
      int dim = d0 + 16*di;
      __bf16 h0,l0,h1,l1,h2,l2,h3,l3;
      split_bf16(vreg[di*4+0],h0,l0); split_bf16(vreg[di*4+1],h1,l1);
      split_bf16(vreg[di*4+2],h2,l2); split_bf16(vreg[di*4+3],h3,l3);
      *(bf16x4*)&VH[dim*72 + k0] = (bf16x4){h0,h1,h2,h3};
      *(bf16x4*)&VL[dim*72 + k0] = (bf16x4){l0,l1,l2,l3};
    }
  };

  load_kv(0);
  #pragma unroll 1
  for (int kt = 0; kt < 10; ++kt) {
    __syncthreads();
    store_kv();
    __syncthreads();
    if (kt < 9) load_kv(kt + 1);   // overlap with compute below

    // ---- S^T = K · Q^T ----
    float s_[4][4];
    #pragma unroll
    for (int nt = 0; nt < 4; ++nt) {
      f32x4 sac = (f32x4){0.f, 0.f, 0.f, 0.f};
      #pragma unroll
      for (int ks = 0; ks < 2; ++ks) {
        const int ko_ = ks*32 + quad*8;
        bf16x8 kh = *(const bf16x8*)&KH[(nt*16 + m)*72 + ko_];
        bf16x8 kl = *(const bf16x8*)&KL[(nt*16 + m)*72 + ko_];
        sac = __builtin_amdgcn_mfma_f32_16x16x32_bf16(kh, qh[ks], sac, 0, 0, 0);
        sac = __builtin_amdgcn_mfma_f32_16x16x32_bf16(kl, qh[ks], sac, 0, 0, 0);
        sac = __builtin_amdgcn_mfma_f32_16x16x32_bf16(kh, ql[ks], sac, 0, 0, 0);
      }
      s_[nt][0] = sac.x; s_[nt][1] = sac.y; s_[nt][2] = sac.z; s_[nt][3] = sac.w;
    }

    // ---- Gaussian bias + masking ----
    #pragma unroll
    for (int nt = 0; nt < 4; ++nt) {
      #pragma unroll
      for (int reg = 0; reg < 4; ++reg) {
        int key = kt*64 + nt*16 + quad*4 + reg;
        float sval = s_[nt][reg];
        float kgf = (float)(key - 1);
        float krf = floorf(kgf * (1.0f/24.0f));
        float kcf = kgf - 24.f*krf;
        float dx = qc - kcf, dy = qr - krf;
        float bias = al * __expf(-(dx*dx*isx + dy*dy*isy));
        bool khas = (key >= 1) && (key < T_);
        sval += (khas && qhas) ? bias : 0.f;
        s_[nt][reg] = (key < T_) ? sval : -1e30f;
      }
    }

    // ---- online softmax ----
    float mx = s_[0][0];
    #pragma unroll
    for (int nt = 0; nt < 4; ++nt)
      #pragma unroll
      for (int reg = 0; reg < 4; ++reg)
        mx = fmaxf(mx, s_[nt][reg]);
    mx = fmaxf(mx, __shfl_xor(mx, 16, 64));
    mx = fmaxf(mx, __shfl_xor(mx, 32, 64));
    float mn = fmaxf(mo, mx);
    float sc = __expf(mo - mn);
    float lt = 0.f;
    #pragma unroll
    for (int nt = 0; nt < 4; ++nt)
      #pragma unroll
      for (int reg = 0; reg < 4; ++reg) {
        float p = __expf(s_[nt][reg] - mn);
        s_[nt][reg] = p;
        lt += p;
      }
    lt += __shfl_xor(lt, 16, 64);
    lt += __shfl_xor(lt, 32, 64);
    lsum = lsum*sc + lt;
    mo = mn;
    #pragma unroll
    for (int nt = 0; nt < 4; ++nt) {
      acc[nt].x *= sc; acc[nt].y *= sc; acc[nt].z *= sc; acc[nt].w *= sc;
    }

    // ---- P^T -> B-frags via ds_bpermute ----
    bf16x8 fh[2], fl[2];
    #pragma unroll
    for (int ks = 0; ks < 2; ++ks) {
      #pragma unroll
      for (int reg = 0; reg < 4; ++reg) {
        float xa0 = bperm_f(addrA, s_[2*ks+0][reg]);
        float xa1 = bperm_f(addrA, s_[2*ks+1][reg]);
        float xb0 = bperm_f(addrB, s_[2*ks+0][reg]);
        float xb1 = bperm_f(addrB, s_[2*ks+1][reg]);
        float va = hiNT ? xa1 : xa0;
        float vb = hiNT ? xb1 : xb0;
        __bf16 h, l;
        split_bf16(va, h, l); fh[ks][reg]   = h; fl[ks][reg]   = l;
        split_bf16(vb, h, l); fh[ks][4+reg] = h; fl[ks][4+reg] = l;
      }
    }

    // ---- O^T += V^T · P^T ----
    #pragma unroll
    for (int nt = 0; nt < 4; ++nt) {
      f32x4 c = acc[nt];
      #pragma unroll
      for (int ks = 0; ks < 2; ++ks) {
        const int ko_ = ks*32 + quad*8;
        bf16x8 vh = *(const bf16x8*)&VH[(nt*16 + m)*72 + ko_];
        bf16x8 vl = *(const bf16x8*)&VL[(nt*16 + m)*72 + ko_];
        c = __builtin_amdgcn_mfma_f32_16x16x32_bf16(vh, fh[ks], c, 0, 0, 0);
        c = __builtin_amdgcn_mfma_f32_16x16x32_bf16(vl, fh[ks], c, 0, 0, 0);
        c = __builtin_amdgcn_mfma_f32_16x16x32_bf16(vh, fl[ks], c, 0, 0, 0);
      }
      acc[nt] = c;
    }
  }

  // ---- epilogue: coalesced float4 stores ----
  if (qvalid) {
    float inv = 1.f / lsum;
    #pragma unroll
    for (int nt = 0; nt < 4; ++nt) {
      float4 o;
      o.x = acc[nt].x * inv;
      o.y = acc[nt].y * inv;
      o.z = acc[nt].z * inv;
      o.w = acc[nt].w * inv;
      *(float4*)(out + ((size_t)b*T_ + row)*H_ + nt*16 + quad*4) = o;
    }
  }
}

extern "C" void kernel_launch(void* const* d_in, const int* in_sizes, int n_in,
                              void* d_out, int out_size, void* d_ws, size_t ws_size,
                              hipStream_t stream) {
  const float* x      = (const float*)d_in[0];
  const float* wq     = (const float*)d_in[1];
  const float* wk     = (const float*)d_in[2];
  const float* wv     = (const float*)d_in[3];
  const float* qg     = (const float*)d_in[4];
  const float* qb     = (const float*)d_in[5];
  const float* kg     = (const float*)d_in[6];
  const float* kb     = (const float*)d_in[7];
  const float* wsig   = (const float*)d_in[8];
  const float* bsig   = (const float*)d_in[9];
  const float* walp   = (const float*)d_in[10];
  const float* balp   = (const float*)d_in[11];
  float* out = (float*)d_out;

  float* ws  = (float*)d_ws;
  const size_t nrow = (size_t)B_ * T_;        // 36928
  float* qo  = ws;
  float* ko  = qo + nrow*H_;
  float* vo  = ko + nrow*H_;
  float* alo = vo + nrow*H_;
  float* sxo = alo + (size_t)B_*N_;
  float* syo = sxo + (size_t)B_*N_;
  __bf16* wsw2 = (__bf16*)(syo + (size_t)B_*N_);   // 24*12288 bf16 = 589824 B

  hipLaunchKernelGGL(prep_w_kernel, dim3(18), dim3(256), 0, stream,
                     wq, wk, wv, wsw2);
  hipLaunchKernelGGL(qkv_ln_kernel, dim3(577), dim3(256), 0, stream,
                     x, wsw2, qg, qb, kg, kb, wsig, bsig, walp, balp,
                     qo, ko, vo, alo, sxo, syo);
  hipLaunchKernelGGL(attn_kernel, dim3(10, B_), dim3(256), 0, stream,
                     qo, ko, vo, alo, sxo, syo, out);
}

// Round 9
// 287.458 us; speedup vs baseline: 1.0640x; 1.0640x over previous
//
#include <hip/hip_runtime.h>
#include <math.h>

#define B_ 64
#define T_ 577
#define E_ 768
#define H_ 64
#define N_ 576
#define GW_ 24

typedef float f32x4 __attribute__((ext_vector_type(4)));
typedef __bf16 bf16x8 __attribute__((ext_vector_type(8)));
typedef __bf16 bf16x4 __attribute__((ext_vector_type(4)));

__device__ inline void split_bf16(float f, __bf16& h, __bf16& l) {
  h = (__bf16)f;
  l = (__bf16)(f - (float)h);
}

__device__ inline float bperm_f(int byte_addr, float x) {
  return __int_as_float(__builtin_amdgcn_ds_bpermute(byte_addr, __float_as_int(x)));
}

// Direct global->LDS DMA, 16 B per lane. LDS dest = wave-uniform base + lane*16.
#define GLOAD_LDS16(G, L)                                                     \
  __builtin_amdgcn_global_load_lds(                                           \
      (const __attribute__((address_space(1))) void*)(G),                     \
      (__attribute__((address_space(3))) void*)(L), 16, 0, 0)

// -------------------- Kernel 0: W -> split-bf16, slot-permuted chunk layout --------------------
// Chunk kc = 12288 bf16: hi[6144] then lo[6144]. Value W[kc*32+g*8+j][n] lives at
// slot(n,g)*8 + j with slot = n*4 + (g ^ (n&3) ^ ((n>>2)&3)).  (unchanged from R8 — verified)
__global__ __launch_bounds__(256) void prep_w_kernel(
    const float* __restrict__ wq, const float* __restrict__ wk, const float* __restrict__ wv,
    __bf16* __restrict__ wsw2)
{
  int t = blockIdx.x * 256 + threadIdx.x;
  if (t >= 24*192) return;
  int kc = t / 192, n = t - kc*192;
  const float* src = (n < 64) ? wq : ((n < 128) ? wk : wv);
  int nn = n & 63;
  int xb = (n & 3) ^ ((n >> 2) & 3);
  size_t cbase = (size_t)kc * 12288;
  #pragma unroll
  for (int g = 0; g < 4; ++g) {
    __bf16 hb[8], lb[8];
    #pragma unroll
    for (int j = 0; j < 8; ++j) {
      float f = src[(size_t)(kc*32 + g*8 + j)*64 + nn];
      split_bf16(f, hb[j], lb[j]);
    }
    int slot = n*4 + (g ^ xb);
    *(bf16x8*)(wsw2 + cbase + slot*8)        = *(bf16x8*)hb;
    *(bf16x8*)(wsw2 + cbase + 6144 + slot*8) = *(bf16x8*)lb;
  }
}

// -------------------- Kernel 1: MFMA qkv + LN + heads (gload_lds B, SINGLE buffer) ----------
// 577 blocks x 64 rows, 4 waves. B frags are ds_read INSIDE the barrier window (with store_A),
// so after sync2 the single B buffer is dead -> next chunk's DMA overwrites it and flies
// across the MFMA phase, draining at the next sync1. LDS stays 50688 B -> 3 blocks/CU.
__global__ __launch_bounds__(256) void qkv_ln_kernel(
    const float* __restrict__ x, const __bf16* __restrict__ wsw2,
    const float* __restrict__ qg, const float* __restrict__ qb,
    const float* __restrict__ kg, const float* __restrict__ kb,
    const float* __restrict__ wsig, const float* __restrict__ bsig,
    const float* __restrict__ walp, const float* __restrict__ balp,
    float* __restrict__ qo, float* __restrict__ ko, float* __restrict__ vo,
    float* __restrict__ alo, float* __restrict__ sxo, float* __restrict__ syo)
{
  // stage: A 64x40 hi/lo (5120 el = 10240 B) + B single 12288 el (24576 B) = 34816 B,
  // aliased by C tile 64x193 f32 + stats = 50432 B -> LDS block 50688 (3 blocks/CU).
  __shared__ __align__(16) float smem[64*193 + 256];
  __bf16* A_hi = (__bf16*)smem;            // 64 x 40
  __bf16* A_lo = A_hi + 2560;
  __bf16* B0   = A_lo + 2560;              // 12288 el, single buffer
  float (*Cs)[193] = (float (*)[193])smem;
  float* mu_q = smem + 64*193;
  float* rs_q = mu_q + 64;
  float* mu_k = rs_q + 64;
  float* rs_k = mu_k + 64;

  const int tid  = threadIdx.x;
  const int lane = tid & 63;
  const int w    = tid >> 6;
  const int quad = lane >> 4;
  const int m    = lane & 15;
  const int rowbase = blockIdx.x << 6;

  f32x4 acc[4][3];
  #pragma unroll
  for (int mt = 0; mt < 4; ++mt)
    #pragma unroll
    for (int nt = 0; nt < 3; ++nt)
      acc[mt][nt] = (f32x4){0.f, 0.f, 0.f, 0.f};

  const int kfrag = quad * 8;
  const int xl    = quad ^ (m & 3) ^ (m >> 2);   // per-lane B slot xor

  // A prefetch registers (depth 1, as R1)
  float4 xr0, xr1;
  const int arow0 = tid >> 3,         ak0 = (tid & 7) * 4;
  const int arow1 = (tid + 256) >> 3, ak1 = (tid & 7) * 4;

  auto load_A = [&](int kc) {
    xr0 = *(const float4*)(x + (size_t)(rowbase + arow0)*E_ + kc*32 + ak0);
    xr1 = *(const float4*)(x + (size_t)(rowbase + arow1)*E_ + kc*32 + ak1);
  };
  auto store_A = [&]() {
    __bf16 h0,l0,h1,l1,h2,l2,h3,l3;
    split_bf16(xr0.x,h0,l0); split_bf16(xr0.y,h1,l1);
    split_bf16(xr0.z,h2,l2); split_bf16(xr0.w,h3,l3);
    *(bf16x4*)&A_hi[arow0*40 + ak0] = (bf16x4){h0,h1,h2,h3};
    *(bf16x4*)&A_lo[arow0*40 + ak0] = (bf16x4){l0,l1,l2,l3};
    split_bf16(xr1.x,h0,l0); split_bf16(xr1.y,h1,l1);
    split_bf16(xr1.z,h2,l2); split_bf16(xr1.w,h3,l3);
    *(bf16x4*)&A_hi[arow1*40 + ak1] = (bf16x4){h0,h1,h2,h3};
    *(bf16x4*)&A_lo[arow1*40 + ak1] = (bf16x4){l0,l1,l2,l3};
  };
  // per wave: 6 DMA calls x 1024 B = 1/4 of the 24576-B chunk
  auto issue_B = [&](int kc) {
    const __bf16* sbase = wsw2 + (size_t)kc*12288 + (size_t)(w*6)*512 + lane*8;
    __bf16* dbase = B0 + (w*6)*512;
    #pragma unroll
    for (int j = 0; j < 6; ++j)
      GLOAD_LDS16(sbase + j*512, dbase + j*512);
  };

  issue_B(0);
  load_A(0);
  #pragma unroll 1
  for (int kc = 0; kc < 24; ++kc) {
    __syncthreads();          // (1) drains vmcnt: B(kc) DMA landed, A(kc) regs ready; prev A readers done
    store_A();
    // B frags for THIS chunk -> registers, inside the barrier window
    bf16x8 bh[3], bl[3];
    #pragma unroll
    for (int nt = 0; nt < 3; ++nt) {
      int slotb = (w*48 + nt*16 + m)*4 + xl;
      bh[nt] = *(const bf16x8*)&B0[slotb*8];
      bl[nt] = *(const bf16x8*)&B0[6144 + slotb*8];
    }
    __syncthreads();          // (2) A visible; ALL waves' B frag reads retired -> B0 is dead
    if (kc < 23) {            // overwrite B0 for kc+1; DMA + A loads fly across the MFMA phase
      issue_B(kc + 1);
      load_A(kc + 1);
    }

    #pragma unroll
    for (int mt = 0; mt < 4; ++mt) {
      bf16x8 ah = *(const bf16x8*)&A_hi[(mt*16 + m)*40 + kfrag];
      bf16x8 al = *(const bf16x8*)&A_lo[(mt*16 + m)*40 + kfrag];
      #pragma unroll
      for (int nt = 0; nt < 3; ++nt) {
        acc[mt][nt] = __builtin_amdgcn_mfma_f32_16x16x32_bf16(ah, bh[nt], acc[mt][nt], 0, 0, 0);
        acc[mt][nt] = __builtin_amdgcn_mfma_f32_16x16x32_bf16(al, bh[nt], acc[mt][nt], 0, 0, 0);
        acc[mt][nt] = __builtin_amdgcn_mfma_f32_16x16x32_bf16(ah, bl[nt], acc[mt][nt], 0, 0, 0);
      }
    }
  }
  __syncthreads();   // all LDS frag reads done before aliasing as C tile

  #pragma unroll
  for (int mt = 0; mt < 4; ++mt)
    #pragma unroll
    for (int nt = 0; nt < 3; ++nt) {
      int row = mt*16 + quad*4;
      int col = w*48 + nt*16 + m;
      Cs[row + 0][col] = acc[mt][nt].x;
      Cs[row + 1][col] = acc[mt][nt].y;
      Cs[row + 2][col] = acc[mt][nt].z;
      Cs[row + 3][col] = acc[mt][nt].w;
    }
  __syncthreads();

  // stats: wave0 -> q rows, wave1 -> k rows (parallel)
  if (tid < 64) {
    float s = 0.f;
    for (int h = 0; h < 64; ++h) s += Cs[tid][h];
    float mu = s * (1.f/64.f);
    float vs = 0.f;
    for (int h = 0; h < 64; ++h) { float d = Cs[tid][h] - mu; vs += d*d; }
    mu_q[tid] = mu;
    rs_q[tid] = rsqrtf(vs*(1.f/64.f) + 1e-5f);
  } else if (tid < 128) {
    int r = tid - 64;
    float s = 0.f;
    for (int h = 0; h < 64; ++h) s += Cs[r][64+h];
    float mu = s * (1.f/64.f);
    float vs = 0.f;
    for (int h = 0; h < 64; ++h) { float d = Cs[r][64+h] - mu; vs += d*d; }
    mu_k[r] = mu;
    rs_k[r] = rsqrtf(vs*(1.f/64.f) + 1e-5f);
  }
  __syncthreads();

  // heads on wave 3 (rows = tid-192), LN-apply on everyone
  if (tid >= 192) {
    int r = tid - 192;
    int mrow = rowbase + r;
    int tindex = mrow % T_;
    if (tindex >= 1) {
      int bb = mrow / T_;
      int g = tindex - 1;
      float mu = mu_q[r], rs = rs_q[r];
      float za = 0.f, z0 = 0.f, z1 = 0.f;
      for (int h = 0; h < 64; ++h) {
        float qv = (Cs[r][h] - mu) * rs * qg[h] + qb[h];
        za += qv * walp[h];
        z0 += qv * wsig[2*h];
        z1 += qv * wsig[2*h+1];
      }
      za += balp[0]; z0 += bsig[0]; z1 += bsig[1];
      float al = fmaxf(za, 0.f) + log1pf(__expf(-fabsf(za)));
      float sx = 1.f/(1.f + __expf(-z0));
      float sy = 1.f/(1.f + __expf(-z1));
      alo[bb*N_ + g] = al;
      sxo[bb*N_ + g] = 0.5f/(sx*sx);
      syo[bb*N_ + g] = 0.5f/(sy*sy);
    }
  }
  // LN-apply + store q,k,v (float4 per thread-iteration)
  for (int idx = tid; idx < 64*48; idx += 256) {
    int r = idx / 48, c4 = (idx - (idx/48)*48) * 4;
    size_t row = (size_t)rowbase + r;
    float4 val = make_float4(Cs[r][c4], Cs[r][c4+1], Cs[r][c4+2], Cs[r][c4+3]);
    if (c4 < 64) {
      float mu = mu_q[r], rs = rs_q[r];
      float4 o;
      o.x = (val.x - mu)*rs*qg[c4+0] + qb[c4+0];
      o.y = (val.y - mu)*rs*qg[c4+1] + qb[c4+1];
      o.z = (val.z - mu)*rs*qg[c4+2] + qb[c4+2];
      o.w = (val.w - mu)*rs*qg[c4+3] + qb[c4+3];
      *(float4*)(qo + row*64 + c4) = o;
    } else if (c4 < 128) {
      int h = c4 - 64;
      float mu = mu_k[r], rs = rs_k[r];
      float4 o;
      o.x = (val.x - mu)*rs*kg[h+0] + kb[h+0];
      o.y = (val.y - mu)*rs*kg[h+1] + kb[h+1];
      o.z = (val.z - mu)*rs*kg[h+2] + kb[h+2];
      o.w = (val.w - mu)*rs*kg[h+3] + kb[h+3];
      *(float4*)(ko + row*64 + h) = o;
    } else {
      *(float4*)(vo + row*64 + (c4-128)) = val;
    }
  }
}

// -------------------- Kernel 2: swapped-operand MFMA flash attention (unchanged) ----------
__global__ __launch_bounds__(256, 4) void attn_kernel(
    const float* __restrict__ q, const float* __restrict__ k, const float* __restrict__ v,
    const float* __restrict__ ala, const float* __restrict__ sxa, const float* __restrict__ sya,
    float* __restrict__ out)
{
  __shared__ __align__(16) __bf16 sm[4*4608];   // 4 regions of 64x72
  __bf16* KH = sm;            __bf16* KL = sm + 4608;
  __bf16* VH = sm + 2*4608;   __bf16* VL = sm + 3*4608;   // V^T: [dim][key]

  const int tid  = threadIdx.x;
  const int lane = tid & 63;
  const int w    = tid >> 6;
  const int quad = lane >> 4;
  const int m    = lane & 15;

  // XCD-aware bijective remap of 640 blocks (8 XCDs x 80)
  const int f       = blockIdx.y * 10 + blockIdx.x;
  const int logical = (f & 7) * 80 + (f >> 3);
  const int b       = logical / 10;
  const int qt      = logical - b * 10;

  const float* qbase = q + (size_t)b * T_ * H_;
  const float* kbase = k + (size_t)b * T_ * H_;
  const float* vbase = v + (size_t)b * T_ * H_;

  // ---- per-lane q-row parameters ----
  const int  row    = qt*64 + w*16 + m;
  const int  rowc   = row < T_ ? row : T_ - 1;
  const bool qvalid = row < T_;
  const bool qhas   = (row >= 1) && qvalid;
  float al = 0.f, isx = 0.f, isy = 0.f, qr = 0.f, qc = 0.f;
  {
    int g = qhas ? row - 1 : 0;
    if (qhas) {
      al  = ala[b*N_ + g] * 0.125f;
      isx = sxa[b*N_ + g];
      isy = sya[b*N_ + g];
      int gr = g / GW_;
      qr = (float)gr;
      qc = (float)(g - gr*GW_);
    }
  }

  // ---- Q into registers, pre-scaled by 1/8, hi/lo split ----
  bf16x8 qh[2], ql[2];
  #pragma unroll
  for (int ks = 0; ks < 2; ++ks) {
    float4 f0 = *(const float4*)(qbase + (size_t)rowc*H_ + ks*32 + quad*8);
    float4 f1 = *(const float4*)(qbase + (size_t)rowc*H_ + ks*32 + quad*8 + 4);
    float fv[8] = {f0.x, f0.y, f0.z, f0.w, f1.x, f1.y, f1.z, f1.w};
    #pragma unroll
    for (int j = 0; j < 8; ++j) {
      float s = fv[j] * 0.125f;
      __bf16 h, l;
      split_bf16(s, h, l);
      qh[ks][j] = h;
      ql[ks][j] = l;
    }
  }

  float mo = -INFINITY, lsum = 0.f;
  f32x4 acc[4];   // O^T: acc[nt].reg = O[d = nt*16+quad*4+reg][q = w*16+m]
  #pragma unroll
  for (int nt = 0; nt < 4; ++nt) acc[nt] = (f32x4){0.f, 0.f, 0.f, 0.f};

  const int  addrA = ((2*(quad & 1))*16 + m) * 4;
  const int  addrB = addrA + 64;
  const bool hiNT  = quad >= 2;

  float4 kreg[4];
  float  vreg[16];
  const int d0 = tid & 15, k0 = (tid >> 4) * 4;

  auto load_kv = [&](int kt) {
    #pragma unroll
    for (int i = 0; i < 4; ++i) {
      int s = tid + 256*i;
      int key = s >> 4, c4 = (s & 15)*4;
      int kgl = kt*64 + key;
      int kcl = kgl < T_ ? kgl : T_ - 1;
      kreg[i] = *(const float4*)(kbase + (size_t)kcl*H_ + c4);
    }
    #pragma unroll
    for (int di = 0; di < 4; ++di)
      #pragma unroll
      for (int ki = 0; ki < 4; ++ki) {
        int kgl = kt*64 + k0 + ki;
        int kcl = kgl < T_ ? kgl : T_ - 1;
        vreg[di*4+ki] = vbase[(size_t)kcl*H_ + d0 + 16*di];
      }
  };
  auto store_kv = [&]() {
    #pragma unroll
    for (int i = 0; i < 4; ++i) {
      int s = tid + 256*i;
      int key = s >> 4, c4 = (s & 15)*4;
      __bf16 h0,l0,h1,l1,h2,l2,h3,l3;
      split_bf16(kreg[i].x,h0,l0); split_bf16(kreg[i].y,h1,l1);
      split_bf16(kreg[i].z,h2,l2); split_bf16(kreg[i].w,h3,l3);
      *(bf16x4*)&KH[key*72 + c4] = (bf16x4){h0,h1,h2,h3};
      *(bf16x4*)&KL[key*72 + c4] = (bf16x4){l0,l1,l2,l3};
    }
    #pragma unroll
    for (int di = 0; di < 4; ++di) {
      int dim = d0 + 16*di;
      __bf16 h0,l0,h1,l1,h2,l2,h3,l3;
      split_bf16(vreg[di*4+0],h0,l0); split_bf16(vreg[di*4+1],h1,l1);
      split_bf16(vreg[di*4+2],h2,l2); split_bf16(vreg[di*4+3],h3,l3);
      *(bf16x4*)&VH[dim*72 + k0] = (bf16x4){h0,h1,h2,h3};
      *(bf16x4*)&VL[dim*72 + k0] = (bf16x4){l0,l1,l2,l3};
    }
  };

  load_kv(0);
  #pragma unroll 1
  for (int kt = 0; kt < 10; ++kt) {
    __syncthreads();
    store_kv();
    __syncthreads();
    if (kt < 9) load_kv(kt + 1);   // overlap with compute below

    // ---- S^T = K · Q^T ----
    float s_[4][4];
    #pragma unroll
    for (int nt = 0; nt < 4; ++nt) {
      f32x4 sac = (f32x4){0.f, 0.f, 0.f, 0.f};
      #pragma unroll
      for (int ks = 0; ks < 2; ++ks) {
        const int ko_ = ks*32 + quad*8;
        bf16x8 kh = *(const bf16x8*)&KH[(nt*16 + m)*72 + ko_];
        bf16x8 kl = *(const bf16x8*)&KL[(nt*16 + m)*72 + ko_];
        sac = __builtin_amdgcn_mfma_f32_16x16x32_bf16(kh, qh[ks], sac, 0, 0, 0);
        sac = __builtin_amdgcn_mfma_f32_16x16x32_bf16(kl, qh[ks], sac, 0, 0, 0);
        sac = __builtin_amdgcn_mfma_f32_16x16x32_bf16(kh, ql[ks], sac, 0, 0, 0);
      }
      s_[nt][0] = sac.x; s_[nt][1] = sac.y; s_[nt][2] = sac.z; s_[nt][3] = sac.w;
    }

    // ---- Gaussian bias + masking ----
    #pragma unroll
    for (int nt = 0; nt < 4; ++nt) {
      #pragma unroll
      for (int reg = 0; reg < 4; ++reg) {
        int key = kt*64 + nt*16 + quad*4 + reg;
        float sval = s_[nt][reg];
        float kgf = (float)(key - 1);
        float krf = floorf(kgf * (1.0f/24.0f));
        float kcf = kgf - 24.f*krf;
        float dx = qc - kcf, dy = qr - krf;
        float bias = al * __expf(-(dx*dx*isx + dy*dy*isy));
        bool khas = (key >= 1) && (key < T_);
        sval += (khas && qhas) ? bias : 0.f;
        s_[nt][reg] = (key < T_) ? sval : -1e30f;
      }
    }

    // ---- online softmax ----
    float mx = s_[0][0];
    #pragma unroll
    for (int nt = 0; nt < 4; ++nt)
      #pragma unroll
      for (int reg = 0; reg < 4; ++reg)
        mx = fmaxf(mx, s_[nt][reg]);
    mx = fmaxf(mx, __shfl_xor(mx, 16, 64));
    mx = fmaxf(mx, __shfl_xor(mx, 32, 64));
    float mn = fmaxf(mo, mx);
    float sc = __expf(mo - mn);
    float lt = 0.f;
    #pragma unroll
    for (int nt = 0; nt < 4; ++nt)
      #pragma unroll
      for (int reg = 0; reg < 4; ++reg) {
        float p = __expf(s_[nt][reg] - mn);
        s_[nt][reg] = p;
        lt += p;
      }
    lt += __shfl_xor(lt, 16, 64);
    lt += __shfl_xor(lt, 32, 64);
    lsum = lsum*sc + lt;
    mo = mn;
    #pragma unroll
    for (int nt = 0; nt < 4; ++nt) {
      acc[nt].x *= sc; acc[nt].y *= sc; acc[nt].z *= sc; acc[nt].w *= sc;
    }

    // ---- P^T -> B-frags via ds_bpermute ----
    bf16x8 fh[2], fl[2];
    #pragma unroll
    for (int ks = 0; ks < 2; ++ks) {
      #pragma unroll
      for (int reg = 0; reg < 4; ++reg) {
        float xa0 = bperm_f(addrA, s_[2*ks+0][reg]);
        float xa1 = bperm_f(addrA, s_[2*ks+1][reg]);
        float xb0 = bperm_f(addrB, s_[2*ks+0][reg]);
        float xb1 = bperm_f(addrB, s_[2*ks+1][reg]);
        float va = hiNT ? xa1 : xa0;
        float vb = hiNT ? xb1 : xb0;
        __bf16 h, l;
        split_bf16(va, h, l); fh[ks][reg]   = h; fl[ks][reg]   = l;
        split_bf16(vb, h, l); fh[ks][4+reg] = h; fl[ks][4+reg] = l;
      }
    }

    // ---- O^T += V^T · P^T ----
    #pragma unroll
    for (int nt = 0; nt < 4; ++nt) {
      f32x4 c = acc[nt];
      #pragma unroll
      for (int ks = 0; ks < 2; ++ks) {
        const int ko_ = ks*32 + quad*8;
        bf16x8 vh = *(const bf16x8*)&VH[(nt*16 + m)*72 + ko_];
        bf16x8 vl = *(const bf16x8*)&VL[(nt*16 + m)*72 + ko_];
        c = __builtin_amdgcn_mfma_f32_16x16x32_bf16(vh, fh[ks], c, 0, 0, 0);
        c = __builtin_amdgcn_mfma_f32_16x16x32_bf16(vl, fh[ks], c, 0, 0, 0);
        c = __builtin_amdgcn_mfma_f32_16x16x32_bf16(vh, fl[ks], c, 0, 0, 0);
      }
      acc[nt] = c;
    }
  }

  // ---- epilogue: coalesced float4 stores ----
  if (qvalid) {
    float inv = 1.f / lsum;
    #pragma unroll
    for (int nt = 0; nt < 4; ++nt) {
      float4 o;
      o.x = acc[nt].x * inv;
      o.y = acc[nt].y * inv;
      o.z = acc[nt].z * inv;
      o.w = acc[nt].w * inv;
      *(float4*)(out + ((size_t)b*T_ + row)*H_ + nt*16 + quad*4) = o;
    }
  }
}

extern "C" void kernel_launch(void* const* d_in, const int* in_sizes, int n_in,
                              void* d_out, int out_size, void* d_ws, size_t ws_size,
                              hipStream_t stream) {
  const float* x      = (const float*)d_in[0];
  const float* wq     = (const float*)d_in[1];
  const float* wk     = (const float*)d_in[2];
  const float* wv     = (const float*)d_in[3];
  const float* qg     = (const float*)d_in[4];
  const float* qb     = (const float*)d_in[5];
  const float* kg     = (const float*)d_in[6];
  const float* kb     = (const float*)d_in[7];
  const float* wsig   = (const float*)d_in[8];
  const float* bsig   = (const float*)d_in[9];
  const float* walp   = (const float*)d_in[10];
  const float* balp   = (const float*)d_in[11];
  float* out = (float*)d_out;

  float* ws  = (float*)d_ws;
  const size_t nrow = (size_t)B_ * T_;        // 36928
  float* qo  = ws;
  float* ko  = qo + nrow*H_;
  float* vo  = ko + nrow*H_;
  float* alo = vo + nrow*H_;
  float* sxo = alo + (size_t)B_*N_;
  float* syo = sxo + (size_t)B_*N_;
  __bf16* wsw2 = (__bf16*)(syo + (size_t)B_*N_);   // 24*12288 bf16 = 589824 B

  hipLaunchKernelGGL(prep_w_kernel, dim3(18), dim3(256), 0, stream,
                     wq, wk, wv, wsw2);
  hipLaunchKernelGGL(qkv_ln_kernel, dim3(577), dim3(256), 0, stream,
                     x, wsw2, qg, qb, kg, kb, wsig, bsig, walp, balp,
                     qo, ko, vo, alo, sxo, syo);
  hipLaunchKernelGGL(attn_kernel, dim3(10, B_), dim3(256), 0, stream,
                     qo, ko, vo, alo, sxo, syo, out);
}